// Round 1
// baseline (387.507 us; speedup 1.0000x reference)
//
#include <hip/hip_runtime.h>
#include <hip/hip_bf16.h>

// similarity_model: wordvec = emb[wordid]; sim = wordvec . emb[v] for all v;
// out = top-(topk+1) values then indices (indices written as float).
// V=200000, D=300. Memory-bound: must stream 240 MB of embedding once.

#define V_ROWS 200000
#define D_DIM 300
#define BLOCKS_A 1024
#define THREADS 256
#define WAVES_PER_BLOCK (THREADS / 64)
#define TOTAL_WAVES (BLOCKS_A * WAVES_PER_BLOCK)
#define MAXK 16
#define NCAND (BLOCKS_A * MAXK)

typedef unsigned long long ull;

// ---- packed (value, index) ordering key -----------------------------------
// Monotone transform of float bits in high 32, ~idx in low 32 so that larger
// packed == (larger value, or equal value with smaller index) — matches jax
// top_k tie-breaking.
__device__ __forceinline__ ull pack_vi(float v, int idx) {
    unsigned int u = __float_as_uint(v);
    u ^= (((unsigned int)((int)u >> 31)) | 0x80000000u);
    return ((ull)u << 32) | (unsigned int)(~(unsigned int)idx);
}
__device__ __forceinline__ float unpack_val(ull p) {
    unsigned int u = (unsigned int)(p >> 32);
    u = (u & 0x80000000u) ? (u ^ 0x80000000u) : ~u;
    return __uint_as_float(u);
}
__device__ __forceinline__ int unpack_idx(ull p) {
    return (int)(~(unsigned int)p);
}

__device__ __forceinline__ ull shflx64(ull v, int off) {
    int lo = __shfl_xor((int)(unsigned int)v, off, 64);
    int hi = __shfl_xor((int)(unsigned int)(v >> 32), off, 64);
    return ((ull)(unsigned int)hi << 32) | (unsigned int)lo;
}
__device__ __forceinline__ ull wave_max64(ull v) {
#pragma unroll
    for (int off = 32; off > 0; off >>= 1) {
        ull o = shflx64(v, off);
        v = (o > v) ? o : v;
    }
    return v;  // uniform across all 64 lanes
}

// Insert key into descending-sorted h[16] (branchless shift, static indices).
__device__ __forceinline__ void insert16(ull (&h)[MAXK], ull key) {
    if (key <= h[MAXK - 1]) return;
    ull prev = ~0ull;  // +inf sentinel
#pragma unroll
    for (int j = 0; j < MAXK; ++j) {
        ull cur = h[j];
        ull mn = (prev < key) ? prev : key;
        h[j] = (mn > cur) ? mn : cur;
        prev = cur;
    }
}

// ---- phase 1: dot products + per-block top-16 -----------------------------
__global__ __launch_bounds__(THREADS) void sim_phase1(const int* __restrict__ wordid,
                                                      const float* __restrict__ emb,
                                                      ull* __restrict__ cands) {
    const int lane = threadIdx.x & 63;
    const int wv = threadIdx.x >> 6;
    const int gwave = blockIdx.x * WAVES_PER_BLOCK + wv;

    // word vector: 75 float4 chunks; lane holds chunk[lane] and chunk[64+lane]
    const int wid = wordid[0];
    const float4* wrow = (const float4*)(emb + (size_t)wid * D_DIM);
    float4 wv0 = wrow[lane];
    float4 wv1 = make_float4(0.f, 0.f, 0.f, 0.f);
    if (lane < 11) wv1 = wrow[64 + lane];

    ull h[MAXK];
#pragma unroll
    for (int j = 0; j < MAXK; ++j) h[j] = 0ull;

#pragma unroll 2
    for (int row = gwave; row < V_ROWS; row += TOTAL_WAVES) {
        const float4* r4 = (const float4*)(emb + (size_t)row * D_DIM);
        float4 a = r4[lane];
        float s = a.x * wv0.x + a.y * wv0.y + a.z * wv0.z + a.w * wv0.w;
        if (lane < 11) {
            float4 b = r4[64 + lane];
            s += b.x * wv1.x + b.y * wv1.y + b.z * wv1.z + b.w * wv1.w;
        }
        // xor-butterfly sum: commutative adds -> bit-identical on all lanes
#pragma unroll
        for (int off = 32; off > 0; off >>= 1) s += __shfl_xor(s, off, 64);
        insert16(h, pack_vi(s, row));  // wave-uniform
    }

    // block merge: each wave's (uniform) top-16 -> LDS, wave 0 extracts 16
    __shared__ ull lds[WAVES_PER_BLOCK * MAXK];
    if (lane == 0) {
#pragma unroll
        for (int j = 0; j < MAXK; ++j) lds[wv * MAXK + j] = h[j];
    }
    __syncthreads();
    if (wv == 0) {
        ull cand = lds[lane];  // 4*16 == 64 == lanes, all real candidates
#pragma unroll
        for (int r = 0; r < MAXK; ++r) {
            ull win = wave_max64(cand);
            if (cand == win) cand = 0ull;  // consume (keys are distinct)
            if (lane == 0) cands[(size_t)blockIdx.x * MAXK + r] = win;
        }
    }
}

// ---- phase 2: merge 16384 candidates -> final top-K -----------------------
__global__ __launch_bounds__(THREADS) void sim_phase2(const ull* __restrict__ cands,
                                                      const int* __restrict__ topk,
                                                      float* __restrict__ out) {
    const int t = threadIdx.x;
    const int lane = t & 63;
    const int wv = t >> 6;
    int K = topk[0] + 1;
    if (K > MAXK) K = MAXK;

    ull h[MAXK];
#pragma unroll
    for (int j = 0; j < MAXK; ++j) h[j] = 0ull;
    for (int j = t; j < NCAND; j += THREADS) insert16(h, cands[j]);

    __shared__ ull lds[WAVES_PER_BLOCK * MAXK];
    // wave merge via head extraction; lane 0 records winners to LDS
#pragma unroll
    for (int r = 0; r < MAXK; ++r) {
        ull head = h[0];
        ull win = wave_max64(head);
        if (head == win) {  // consume: shift left (static indices only)
#pragma unroll
            for (int j = 0; j < MAXK - 1; ++j) h[j] = h[j + 1];
            h[MAXK - 1] = 0ull;
        }
        if (lane == 0) lds[wv * MAXK + r] = win;
    }
    __syncthreads();
    if (wv == 0) {
        ull cand = lds[lane];
#pragma unroll
        for (int r = 0; r < MAXK; ++r) {
            ull win = wave_max64(cand);
            if (cand == win) cand = 0ull;
            if (lane == 0 && r < K) {
                out[r] = unpack_val(win);
                out[K + r] = (float)unpack_idx(win);
            }
        }
    }
}

extern "C" void kernel_launch(void* const* d_in, const int* in_sizes, int n_in,
                              void* d_out, int out_size, void* d_ws, size_t ws_size,
                              hipStream_t stream) {
    const int* wordid = (const int*)d_in[0];
    const float* emb = (const float*)d_in[1];
    const int* topk = (const int*)d_in[2];
    float* out = (float*)d_out;
    ull* cands = (ull*)d_ws;  // NCAND * 8 = 128 KB

    sim_phase1<<<BLOCKS_A, THREADS, 0, stream>>>(wordid, emb, cands);
    sim_phase2<<<1, THREADS, 0, stream>>>(cands, topk, out);
}